// Round 1
// baseline (1396.299 us; speedup 1.0000x reference)
//
#include <hip/hip_runtime.h>
#include <cmath>

#define F_IN 500
#define HD 64
#define NL 8
#define NRANK 3
#define NOUT 40
#define NPACK 2145  // 65*66/2 packed upper-tri of extended [h,1] quadratic form

// ---------------- CSR build ----------------
__global__ __launch_bounds__(256) void k_zero(int* counts, float* linbuf, float* cbuf, int N) {
  int i = blockIdx.x * 256 + threadIdx.x;
  if (i < N) counts[i] = 0;
  if (i < NOUT * HD) linbuf[i] = 0.f;
  if (i < NOUT) cbuf[i] = 0.f;
}

__global__ __launch_bounds__(256) void k_count(const int* __restrict__ row, int* counts, int E) {
  int e = blockIdx.x * 256 + threadIdx.x;
  if (e < E) atomicAdd(&counts[row[e]], 1);
}

__global__ __launch_bounds__(1024) void k_scan(const int* __restrict__ counts, int* __restrict__ rowptr,
                                               int* __restrict__ cursor, int N, int E) {
  __shared__ int sh[1024];
  __shared__ int s_off;
  int t = threadIdx.x;
  if (t == 0) s_off = 0;
  __syncthreads();
  for (int base = 0; base < N; base += 1024) {
    int i = base + t;
    int c = (i < N) ? counts[i] : 0;
    sh[t] = c;
    __syncthreads();
    for (int d = 1; d < 1024; d <<= 1) {
      int v = (t >= d) ? sh[t - d] : 0;
      __syncthreads();
      sh[t] += v;
      __syncthreads();
    }
    int excl = sh[t] - c + s_off;
    if (i < N) { rowptr[i] = excl; cursor[i] = excl; }
    __syncthreads();
    if (t == 0) s_off += sh[1023];
    __syncthreads();
  }
  if (t == 0) rowptr[N] = E;
}

__global__ __launch_bounds__(256) void k_fill(const int* __restrict__ row, const int* __restrict__ col,
                                              const float* __restrict__ w, int* cursor,
                                              int2* __restrict__ colw, int E) {
  int e = blockIdx.x * 256 + threadIdx.x;
  if (e < E) {
    int r = row[e];
    int p = atomicAdd(&cursor[r], 1);
    colw[p] = make_int2(col[e], __float_as_int(w[e]));
  }
}

// ---------------- input GEMM: h0 = relu(x @ W_in + b) ----------------
__global__ __launch_bounds__(256) void k_gemm_in(const float* __restrict__ x, const float* __restrict__ W,
                                                 const float* __restrict__ b, float* __restrict__ h0, int N) {
  __shared__ float xs[64][52];
  __shared__ float ws_[50][64];
  int tid = threadIdx.x;
  int tx = tid & 15, ty = tid >> 4;
  int n0 = blockIdx.x * 64;
  float acc[4][4] = {};
  for (int k0 = 0; k0 < F_IN; k0 += 50) {
    for (int idx = tid; idx < 64 * 50; idx += 256) {
      int nn = idx / 50, kk = idx - nn * 50;
      int n = n0 + nn;
      xs[nn][kk] = (n < N) ? x[(size_t)n * F_IN + k0 + kk] : 0.f;
    }
    for (int idx = tid; idx < 50 * 64; idx += 256) {
      int kk = idx >> 6, d = idx & 63;
      ws_[kk][d] = W[(size_t)(k0 + kk) * HD + d];
    }
    __syncthreads();
    for (int kk = 0; kk < 50; ++kk) {
      float av[4], bv[4];
#pragma unroll
      for (int i = 0; i < 4; ++i) av[i] = xs[ty * 4 + i][kk];
      float4 b4 = *(const float4*)&ws_[kk][tx * 4];
      bv[0] = b4.x; bv[1] = b4.y; bv[2] = b4.z; bv[3] = b4.w;
#pragma unroll
      for (int i = 0; i < 4; ++i)
#pragma unroll
        for (int j = 0; j < 4; ++j) acc[i][j] = fmaf(av[i], bv[j], acc[i][j]);
    }
    __syncthreads();
  }
#pragma unroll
  for (int i = 0; i < 4; ++i) {
    int n = n0 + ty * 4 + i;
    if (n < N) {
#pragma unroll
      for (int j = 0; j < 4; ++j) {
        int d = tx * 4 + j;
        float v = acc[i][j] + b[d];
        h0[(size_t)n * HD + d] = v > 0.f ? v : 0.f;
      }
    }
  }
}

// ---------------- GCN2 layer: CSR SpMM + residual + matvec + relu ----------------
__global__ __launch_bounds__(256) void k_layer(const float* __restrict__ hin, const float* __restrict__ h0,
                                               const int* __restrict__ rowptr, const int2* __restrict__ colw,
                                               const float* __restrict__ convW, float beta,
                                               float* __restrict__ hout, int N) {
  __shared__ float Wl[64][64];
  __shared__ float sup[4][64];
  int tid = threadIdx.x;
  int wv = tid >> 6, t = tid & 63;
  for (int idx = tid; idx < 4096; idx += 256) Wl[idx >> 6][idx & 63] = convW[idx];
  int n = blockIdx.x * 4 + wv;
  float s = 0.f;
  if (n < N) {
    float acc = 0.f;
    int e0 = rowptr[n], e1 = rowptr[n + 1];
    for (int e = e0; e < e1; ++e) {
      int2 cw = colw[e];
      acc = fmaf(__int_as_float(cw.y), hin[(size_t)cw.x * HD + t], acc);
    }
    s = 0.9f * acc + 0.1f * h0[(size_t)n * HD + t];
    sup[wv][t] = s;
  }
  __syncthreads();
  if (n < N) {
    float mv = 0.f;
#pragma unroll
    for (int h = 0; h < 64; ++h) mv = fmaf(sup[wv][h], Wl[h][t], mv);
    float v = (1.f - beta) * s + beta * mv;
    hout[(size_t)n * HD + t] = v > 0.f ? v : 0.f;
  }
}

// ---------------- packed-index tables ----------------
__global__ __launch_bounds__(256) void k_tabs(int* mtab, int* ltab) {
  int j = blockIdx.x * 256 + threadIdx.x;
  if (j >= NPACK) return;
  int m = 0;
  while (m < 64 && (m + 1) * 65 - (m + 1) * m / 2 <= j) ++m;
  int off = m * 65 - m * (m - 1) / 2;
  mtab[j] = m;
  ltab[j] = m + (j - off);
}

// ---------------- T[r,o] = Wo_o @ V_r^T  (+ linear/const bias terms) ----------------
__global__ __launch_bounds__(256) void k_T(const float* __restrict__ W_out, const float* __restrict__ V_W,
                                           const float* __restrict__ V_b, const float* __restrict__ U_W,
                                           const float* __restrict__ U_b,
                                           float* __restrict__ Tbuf, float* linbuf, float* cbuf) {
  int o = blockIdx.x % NOUT;
  int r = blockIdx.x / NOUT;
  __shared__ float Wo[64][65];
  __shared__ float Vs[64][65];
  __shared__ float t1[64], t2[64];
  int tid = threadIdx.x;
  int tx = tid & 15, ty = tid >> 4;
  for (int idx = tid; idx < 4096; idx += 256) {
    int m = idx >> 6, l = idx & 63;
    Wo[m][l] = W_out[(size_t)idx * NOUT + o];
    Vs[m][l] = V_W[(size_t)(r * 64 + m) * 64 + l];
  }
  __syncthreads();
  float acc[4][4] = {};
  for (int l = 0; l < 64; ++l) {
    float av[4], bv[4];
#pragma unroll
    for (int i = 0; i < 4; ++i) av[i] = Wo[ty * 4 + i][l];
#pragma unroll
    for (int j = 0; j < 4; ++j) bv[j] = Vs[tx * 4 + j][l];
#pragma unroll
    for (int i = 0; i < 4; ++i)
#pragma unroll
      for (int j = 0; j < 4; ++j) acc[i][j] = fmaf(av[i], bv[j], acc[i][j]);
  }
#pragma unroll
  for (int i = 0; i < 4; ++i)
#pragma unroll
    for (int j = 0; j < 4; ++j)
      Tbuf[(((size_t)r * NOUT + o) * 64 + ty * 4 + i) * 64 + tx * 4 + j] = acc[i][j];
  if (tid < 64) {
    float s1 = 0.f, s2 = 0.f;
    for (int l = 0; l < 64; ++l) s1 = fmaf(Wo[tid][l], V_b[r * 64 + l], s1);
    for (int m = 0; m < 64; ++m) s2 = fmaf(Wo[m][tid], U_b[r * 64 + m], s2);
    t1[tid] = s1;
    t2[tid] = s2;
  }
  __syncthreads();
  if (tid < 64) {
    float s = 0.f, s2 = 0.f;
    for (int m = 0; m < 64; ++m) s = fmaf(U_W[(size_t)(r * 64 + tid) * 64 + m], t1[m], s);
    for (int l = 0; l < 64; ++l) s2 = fmaf(Vs[tid][l], t2[l], s2);
    atomicAdd(&linbuf[o * 64 + tid], s + s2);
  }
  if (tid == 0) {
    float s = 0.f;
    for (int m = 0; m < 64; ++m) s = fmaf(U_b[r * 64 + m], t1[m], s);
    atomicAdd(&cbuf[o], s);
  }
}

// ---------------- Q_o = sum_r U_r @ T[r,o]; pack symmetric 2145 coeffs ----------------
__global__ __launch_bounds__(256) void k_Q(const float* __restrict__ U_W, const float* __restrict__ Tbuf,
                                           const float* __restrict__ linbuf, const float* __restrict__ cbuf,
                                           const float* __restrict__ b_out,
                                           const int* __restrict__ mtab, const int* __restrict__ ltab,
                                           float* __restrict__ Csym) {
  int o = blockIdx.x;
  __shared__ float Us[64][65];
  __shared__ float Tb[64][65];
  __shared__ float Q[64][65];
  int tid = threadIdx.x, tx = tid & 15, ty = tid >> 4;
  float acc[4][4] = {};
  for (int r = 0; r < NRANK; ++r) {
    for (int idx = tid; idx < 4096; idx += 256) {
      int a = idx >> 6, mm = idx & 63;
      Us[a][mm] = U_W[(size_t)(r * 64 + a) * 64 + mm];
      Tb[a][mm] = Tbuf[(((size_t)r * NOUT + o) * 64 + a) * 64 + mm];
    }
    __syncthreads();
    for (int mm = 0; mm < 64; ++mm) {
      float av[4], bv[4];
#pragma unroll
      for (int i = 0; i < 4; ++i) av[i] = Us[ty * 4 + i][mm];
#pragma unroll
      for (int j = 0; j < 4; ++j) bv[j] = Tb[mm][tx * 4 + j];
#pragma unroll
      for (int i = 0; i < 4; ++i)
#pragma unroll
        for (int j = 0; j < 4; ++j) acc[i][j] = fmaf(av[i], bv[j], acc[i][j]);
    }
    __syncthreads();
  }
#pragma unroll
  for (int i = 0; i < 4; ++i)
#pragma unroll
    for (int j = 0; j < 4; ++j) Q[ty * 4 + i][tx * 4 + j] = acc[i][j];
  __syncthreads();
  for (int j = tid; j < NPACK; j += 256) {
    int m = mtab[j], l = ltab[j];
    float v;
    if (l < 64) v = (m == l) ? Q[m][m] : Q[m][l] + Q[l][m];
    else if (m < 64) v = linbuf[o * 64 + m];
    else v = cbuf[o] + b_out[o];
    Csym[(size_t)j * NOUT + o] = v;
  }
}

// ---------------- logits[n,o] = e_n^T Qe_o e_n  (packed symmetric GEMM) ----------------
__global__ __launch_bounds__(256) void k_logits(const float* __restrict__ h, const float* __restrict__ Csym,
                                                const int* __restrict__ mtab, const int* __restrict__ ltab,
                                                float* __restrict__ logits, int N) {
  __shared__ float hT[66][132];
  __shared__ float Cs[64][40];
  int tid = threadIdx.x;
  int og = tid & 7, ng = tid >> 3;
  int n0 = blockIdx.x * 128;
  for (int idx = tid; idx < 128 * 64; idx += 256) {
    int n = idx >> 6, f = idx & 63;
    hT[f][n] = (n0 + n < N) ? h[(size_t)(n0 + n) * HD + f] : 0.f;
  }
  if (tid < 128) hT[64][tid] = 1.f;
  float acc[4][5] = {};
  for (int jc = 0; jc < NPACK; jc += 64) {
    int jn = NPACK - jc < 64 ? NPACK - jc : 64;
    __syncthreads();
    for (int idx = tid; idx < jn * NOUT; idx += 256) {
      int jj = idx / NOUT;
      Cs[jj][idx - jj * NOUT] = Csym[(size_t)jc * NOUT + idx];
    }
    __syncthreads();
    int m = mtab[jc], l = ltab[jc];
    float4 hm = *(const float4*)&hT[m][ng * 4];
    for (int jj = 0; jj < jn; ++jj) {
      float4 hl = *(const float4*)&hT[l][ng * 4];
      float p0 = hm.x * hl.x, p1 = hm.y * hl.y, p2 = hm.z * hl.z, p3 = hm.w * hl.w;
#pragma unroll
      for (int k = 0; k < 5; ++k) {
        float c = Cs[jj][og * 5 + k];
        acc[0][k] = fmaf(p0, c, acc[0][k]);
        acc[1][k] = fmaf(p1, c, acc[1][k]);
        acc[2][k] = fmaf(p2, c, acc[2][k]);
        acc[3][k] = fmaf(p3, c, acc[3][k]);
      }
      if (++l > 64) { ++m; l = m; hm = *(const float4*)&hT[m][ng * 4]; }
    }
  }
#pragma unroll
  for (int i = 0; i < 4; ++i) {
    int n = n0 + ng * 4 + i;
    if (n < N) {
#pragma unroll
      for (int k = 0; k < 5; ++k) logits[(size_t)n * NOUT + og * 5 + k] = acc[i][k];
    }
  }
}

// ---------------- expmap0 + proj + log_softmax ----------------
__global__ __launch_bounds__(256) void k_epi(const float* __restrict__ logits, float* __restrict__ out, int N) {
  int n = blockIdx.x * 256 + threadIdx.x;
  if (n >= N) return;
  float v[40];
  const float4* p = (const float4*)(logits + (size_t)n * NOUT);
#pragma unroll
  for (int i = 0; i < 10; ++i) {
    float4 t = p[i];
    v[4 * i] = t.x; v[4 * i + 1] = t.y; v[4 * i + 2] = t.z; v[4 * i + 3] = t.w;
  }
  float s = 0.f;
#pragma unroll
  for (int i = 0; i < 40; ++i) s = fmaf(v[i], v[i], s);
  float norm = sqrtf(s);
  float un = fmaxf(norm, 1e-15f);
  float sc = tanhf(un) / un;
  float s2 = 0.f;
#pragma unroll
  for (int i = 0; i < 40; ++i) { v[i] *= sc; s2 = fmaf(v[i], v[i], s2); }
  float ny = fmaxf(sqrtf(s2), 1e-15f);
  float maxn = 1.0f - 4e-3f;
  if (ny > maxn) {
    float f = maxn / ny;
#pragma unroll
    for (int i = 0; i < 40; ++i) v[i] *= f;
  }
  float vmax = v[0];
#pragma unroll
  for (int i = 1; i < 40; ++i) vmax = fmaxf(vmax, v[i]);
  float se = 0.f;
#pragma unroll
  for (int i = 0; i < 40; ++i) se += expf(v[i] - vmax);
  float lse = logf(se);
  float4* q = (float4*)(out + (size_t)n * NOUT);
#pragma unroll
  for (int i = 0; i < 10; ++i) {
    float4 t;
    t.x = v[4 * i] - vmax - lse;
    t.y = v[4 * i + 1] - vmax - lse;
    t.z = v[4 * i + 2] - vmax - lse;
    t.w = v[4 * i + 3] - vmax - lse;
    q[i] = t;
  }
}

extern "C" void kernel_launch(void* const* d_in, const int* in_sizes, int n_in,
                              void* d_out, int out_size, void* d_ws, size_t ws_size,
                              hipStream_t stream) {
  const float* x = (const float*)d_in[0];
  const int* erow = (const int*)d_in[1];
  const int* ecol = (const int*)d_in[2];
  const float* ew = (const float*)d_in[3];
  const float* W_in = (const float*)d_in[4];
  const float* b_in = (const float*)d_in[5];
  const float* conv_W = (const float*)d_in[6];
  const float* U_W = (const float*)d_in[7];
  const float* U_b = (const float*)d_in[8];
  const float* V_W = (const float*)d_in[9];
  const float* V_b = (const float*)d_in[10];
  const float* W_out = (const float*)d_in[11];
  const float* b_out = (const float*)d_in[12];
  int N = in_sizes[0] / F_IN;
  int E = in_sizes[1];
  float* out = (float*)d_out;

  char* base = (char*)d_ws;
  size_t off = 0;
  auto alloc = [&](size_t bytes) -> void* {
    void* p = base + off;
    off += (bytes + 255) & ~(size_t)255;
    return p;
  };
  float* h0 = (float*)alloc((size_t)N * HD * 4);
  float* hA = (float*)alloc((size_t)N * HD * 4);
  float* hB = (float*)alloc((size_t)N * HD * 4);
  int* rowptr = (int*)alloc((size_t)(N + 1) * 4);
  int* cursor = (int*)alloc((size_t)N * 4);
  int* counts = (int*)alloc((size_t)N * 4);
  int2* colw = (int2*)alloc((size_t)E * 8);
  float* Tbuf = (float*)alloc((size_t)NRANK * NOUT * 64 * 64 * 4);
  float* Csym = (float*)alloc((size_t)NPACK * NOUT * 4);
  float* linbuf = (float*)alloc(NOUT * 64 * 4);
  float* cbuf = (float*)alloc(NOUT * 4);
  int* mtab = (int*)alloc(NPACK * 4);
  int* ltab = (int*)alloc(NPACK * 4);
  float* logits = hA;  // reuse: free after layer 6; final h lives in hB

  k_zero<<<(N + 255) / 256, 256, 0, stream>>>(counts, linbuf, cbuf, N);
  k_count<<<(E + 255) / 256, 256, 0, stream>>>(erow, counts, E);
  k_scan<<<1, 1024, 0, stream>>>(counts, rowptr, cursor, N, E);
  k_fill<<<(E + 255) / 256, 256, 0, stream>>>(erow, ecol, ew, cursor, colw, E);
  k_gemm_in<<<(N + 63) / 64, 256, 0, stream>>>(x, W_in, b_in, h0, N);
  k_tabs<<<(NPACK + 255) / 256, 256, 0, stream>>>(mtab, ltab);
  k_T<<<NRANK * NOUT, 256, 0, stream>>>(W_out, V_W, V_b, U_W, U_b, Tbuf, linbuf, cbuf);
  k_Q<<<NOUT, 256, 0, stream>>>(U_W, Tbuf, linbuf, cbuf, b_out, mtab, ltab, Csym);

  const float* hin = h0;
  float* hout = hA;
  for (int l = 0; l < NL; ++l) {
    float beta = (float)std::log(0.5 / (double)(l + 1) + 1.0);
    k_layer<<<(N + 3) / 4, 256, 0, stream>>>(hin, h0, rowptr, colw, conv_W + (size_t)l * HD * HD,
                                             beta, hout, N);
    hin = hout;
    hout = (hout == hA) ? hB : hA;
  }
  // after 8 layers the final h is in hB; hA is reused as the logits buffer
  k_logits<<<(N + 127) / 128, 256, 0, stream>>>(hin, Csym, mtab, ltab, logits, N);
  k_epi<<<(N + 255) / 256, 256, 0, stream>>>(logits, out, N);
}

// Round 2
// 1064.743 us; speedup vs baseline: 1.3114x; 1.3114x over previous
//
#include <hip/hip_runtime.h>
#include <cmath>

#define F_IN 500
#define HD 64
#define NL 8
#define NRANK 3
#define NOUT 40
#define NGRP 300   // 297 real (m,l0) groups of 8 + 3 zero pads -> K = 2400
#define NCHUNK 75  // 2400 / 32

typedef __attribute__((ext_vector_type(8))) short short8v;
typedef __attribute__((ext_vector_type(4))) float float4v;

__device__ __forceinline__ float bf2f(ushort u) {
  union { unsigned int i; float f; } v;
  v.i = ((unsigned int)u) << 16;
  return v.f;
}
__device__ __forceinline__ ushort f2bf(float f) {
  union { float f; unsigned int i; } v;
  v.f = f;
  unsigned int b = v.i;
  return (ushort)((b + 0x7FFFu + ((b >> 16) & 1u)) >> 16);
}

// ---------------- zero init ----------------
__global__ __launch_bounds__(256) void k_zero(int* counts, float* linbuf, float* cbuf,
                                              ushort4* bfrag4, int N) {
  int i = blockIdx.x * 256 + threadIdx.x;
  if (i < N) counts[i] = 0;
  if (i < NOUT * HD) linbuf[i] = 0.f;
  if (i < NOUT) cbuf[i] = 0.f;
  if (i < NCHUNK * 3 * 64 * 2) bfrag4[i] = make_ushort4(0, 0, 0, 0);
}

__global__ __launch_bounds__(256) void k_count(const int* __restrict__ row, int* counts, int E) {
  int e = blockIdx.x * 256 + threadIdx.x;
  if (e < E) atomicAdd(&counts[row[e]], 1);
}

// ---------------- parallel scan (3 kernels) ----------------
__global__ __launch_bounds__(1024) void k_scan1(const int* __restrict__ counts, int* __restrict__ rowptr,
                                                int* __restrict__ bsum, int N) {
  __shared__ int sh[1024];
  int t = threadIdx.x, i = blockIdx.x * 1024 + t;
  int c = (i < N) ? counts[i] : 0;
  sh[t] = c;
  __syncthreads();
  for (int d = 1; d < 1024; d <<= 1) {
    int v = (t >= d) ? sh[t - d] : 0;
    __syncthreads();
    sh[t] += v;
    __syncthreads();
  }
  if (i < N) rowptr[i] = sh[t] - c;  // block-local exclusive
  if (t == 1023) bsum[blockIdx.x] = sh[1023];
}

__global__ __launch_bounds__(64) void k_scan2(const int* __restrict__ bsum, int* __restrict__ boff, int G) {
  int t = threadIdx.x;
  int base = 0;
  for (int s = 0; s < G; s += 64) {
    int i = s + t;
    int v = (i < G) ? bsum[i] : 0;
    int orig = v;
    for (int d = 1; d < 64; d <<= 1) {
      int u = __shfl_up(v, d, 64);
      if (t >= d) v += u;
    }
    if (i < G) boff[i] = base + v - orig;
    base += __shfl(v, 63, 64);
  }
}

__global__ __launch_bounds__(1024) void k_scan3(int* __restrict__ rowptr, int* __restrict__ cursor,
                                                const int* __restrict__ boff, int N, int E) {
  int i = blockIdx.x * 1024 + threadIdx.x;
  if (i < N) {
    int v = rowptr[i] + boff[blockIdx.x];
    rowptr[i] = v;
    cursor[i] = v;
  }
  if (i == 0) rowptr[N] = E;
}

__global__ __launch_bounds__(256) void k_fill(const int* __restrict__ row, const int* __restrict__ col,
                                              const float* __restrict__ w, int* cursor,
                                              int2* __restrict__ colw, int E) {
  int e = blockIdx.x * 256 + threadIdx.x;
  if (e < E) {
    int r = row[e];
    int p = atomicAdd(&cursor[r], 1);
    colw[p] = make_int2(col[e], __float_as_int(w[e]));
  }
}

// ---------------- input GEMM: h0 = relu(x @ W_in + b) ----------------
__global__ __launch_bounds__(256) void k_gemm_in(const float* __restrict__ x, const float* __restrict__ W,
                                                 const float* __restrict__ b, float* __restrict__ h0,
                                                 ushort* __restrict__ h0bf, int N) {
  __shared__ float xs[64][52];
  __shared__ float ws_[50][64];
  int tid = threadIdx.x;
  int tx = tid & 15, ty = tid >> 4;
  int n0 = blockIdx.x * 64;
  float acc[4][4] = {};
  for (int k0 = 0; k0 < F_IN; k0 += 50) {
    for (int idx = tid; idx < 64 * 50; idx += 256) {
      int nn = idx / 50, kk = idx - nn * 50;
      int n = n0 + nn;
      xs[nn][kk] = (n < N) ? x[(size_t)n * F_IN + k0 + kk] : 0.f;
    }
    for (int idx = tid; idx < 50 * 64; idx += 256) {
      int kk = idx >> 6, d = idx & 63;
      ws_[kk][d] = W[(size_t)(k0 + kk) * HD + d];
    }
    __syncthreads();
    for (int kk = 0; kk < 50; ++kk) {
      float av[4], bv[4];
#pragma unroll
      for (int i = 0; i < 4; ++i) av[i] = xs[ty * 4 + i][kk];
      float4 b4 = *(const float4*)&ws_[kk][tx * 4];
      bv[0] = b4.x; bv[1] = b4.y; bv[2] = b4.z; bv[3] = b4.w;
#pragma unroll
      for (int i = 0; i < 4; ++i)
#pragma unroll
        for (int j = 0; j < 4; ++j) acc[i][j] = fmaf(av[i], bv[j], acc[i][j]);
    }
    __syncthreads();
  }
#pragma unroll
  for (int i = 0; i < 4; ++i) {
    int n = n0 + ty * 4 + i;
    if (n < N) {
#pragma unroll
      for (int j = 0; j < 4; ++j) {
        int d = tx * 4 + j;
        float v = acc[i][j] + b[d];
        v = v > 0.f ? v : 0.f;
        h0[(size_t)n * HD + d] = v;
        h0bf[(size_t)n * HD + d] = f2bf(v);
      }
    }
  }
}

// ---------------- GCN2 layer: CSR SpMM (bf16 gather) + residual + matvec + relu ----------------
__global__ __launch_bounds__(256) void k_layer(const ushort* __restrict__ hinbf, const float* __restrict__ h0,
                                               const int* __restrict__ rowptr, const int2* __restrict__ colw,
                                               const float* __restrict__ convW, float beta,
                                               ushort* __restrict__ houtbf, int N) {
  __shared__ float Wl[64][64];
  __shared__ float sup[4][64];
  int tid = threadIdx.x;
  int wv = tid >> 6, t = tid & 63;
  for (int idx = tid; idx < 4096; idx += 256) Wl[idx >> 6][idx & 63] = convW[idx];
  int n = blockIdx.x * 4 + wv;
  float s = 0.f;
  if (n < N) {
    float acc = 0.f;
    int e0 = rowptr[n], e1 = rowptr[n + 1];
    for (int e = e0; e < e1; ++e) {
      int2 cw = colw[e];
      acc = fmaf(__int_as_float(cw.y), bf2f(hinbf[(size_t)cw.x * HD + t]), acc);
    }
    s = 0.9f * acc + 0.1f * h0[(size_t)n * HD + t];
    sup[wv][t] = s;
  }
  __syncthreads();
  if (n < N) {
    float mv = 0.f;
#pragma unroll
    for (int h = 0; h < 64; ++h) mv = fmaf(sup[wv][h], Wl[h][t], mv);
    float v = (1.f - beta) * s + beta * mv;
    v = v > 0.f ? v : 0.f;
    houtbf[(size_t)n * HD + t] = f2bf(v);
  }
}

// ---------------- group table: g -> (m, l0), rows of packed upper-tri padded to 8 ----------------
__global__ __launch_bounds__(512) void k_gtab(int2* __restrict__ gtab) {
  int g = threadIdx.x;
  if (g >= NGRP) return;
  int m = 64, l0 = 65;  // pad default (coef 0)
  if (g < 297) {
    int cum = 0;
    for (int mm = 0; mm < 65; ++mm) {
      int ng = (65 - mm + 7) >> 3;
      if (g < cum + ng) { m = mm; l0 = mm + (g - cum) * 8; break; }
      cum += ng;
    }
  }
  gtab[g] = make_int2(m, l0);
}

// ---------------- T[r,o] = Wo_o @ V_r^T  (+ linear/const bias terms) ----------------
__global__ __launch_bounds__(256) void k_T(const float* __restrict__ W_out, const float* __restrict__ V_W,
                                           const float* __restrict__ V_b, const float* __restrict__ U_W,
                                           const float* __restrict__ U_b,
                                           float* __restrict__ Tbuf, float* linbuf, float* cbuf) {
  int o = blockIdx.x % NOUT;
  int r = blockIdx.x / NOUT;
  __shared__ float Wo[64][65];
  __shared__ float Vs[64][65];
  __shared__ float t1[64], t2[64];
  int tid = threadIdx.x;
  int tx = tid & 15, ty = tid >> 4;
  for (int idx = tid; idx < 4096; idx += 256) {
    int m = idx >> 6, l = idx & 63;
    Wo[m][l] = W_out[(size_t)idx * NOUT + o];
    Vs[m][l] = V_W[(size_t)(r * 64 + m) * 64 + l];
  }
  __syncthreads();
  float acc[4][4] = {};
  for (int l = 0; l < 64; ++l) {
    float av[4], bv[4];
#pragma unroll
    for (int i = 0; i < 4; ++i) av[i] = Wo[ty * 4 + i][l];
#pragma unroll
    for (int j = 0; j < 4; ++j) bv[j] = Vs[tx * 4 + j][l];
#pragma unroll
    for (int i = 0; i < 4; ++i)
#pragma unroll
      for (int j = 0; j < 4; ++j) acc[i][j] = fmaf(av[i], bv[j], acc[i][j]);
  }
#pragma unroll
  for (int i = 0; i < 4; ++i)
#pragma unroll
    for (int j = 0; j < 4; ++j)
      Tbuf[(((size_t)r * NOUT + o) * 64 + ty * 4 + i) * 64 + tx * 4 + j] = acc[i][j];
  if (tid < 64) {
    float s1 = 0.f, s2 = 0.f;
    for (int l = 0; l < 64; ++l) s1 = fmaf(Wo[tid][l], V_b[r * 64 + l], s1);
    for (int m = 0; m < 64; ++m) s2 = fmaf(Wo[m][tid], U_b[r * 64 + m], s2);
    t1[tid] = s1;
    t2[tid] = s2;
  }
  __syncthreads();
  if (tid < 64) {
    float s = 0.f, s2 = 0.f;
    for (int m = 0; m < 64; ++m) s = fmaf(U_W[(size_t)(r * 64 + tid) * 64 + m], t1[m], s);
    for (int l = 0; l < 64; ++l) s2 = fmaf(Vs[tid][l], t2[l], s2);
    atomicAdd(&linbuf[o * 64 + tid], s + s2);
  }
  if (tid == 0) {
    float s = 0.f;
    for (int m = 0; m < 64; ++m) s = fmaf(U_b[r * 64 + m], t1[m], s);
    atomicAdd(&cbuf[o], s);
  }
}

// ---------------- Q_o = sum_r U_r @ T[r,o]; pack bf16 B-fragments in MFMA lane layout ----------------
__global__ __launch_bounds__(256) void k_Q(const float* __restrict__ U_W, const float* __restrict__ Tbuf,
                                           const float* __restrict__ linbuf, const float* __restrict__ cbuf,
                                           const float* __restrict__ b_out,
                                           const int2* __restrict__ gtab, ushort* __restrict__ Bfrag) {
  int o = blockIdx.x;
  __shared__ float Us[64][65];
  __shared__ float Tb[64][65];
  __shared__ float Q[64][65];
  int tid = threadIdx.x, tx = tid & 15, ty = tid >> 4;
  float acc[4][4] = {};
  for (int r = 0; r < NRANK; ++r) {
    for (int idx = tid; idx < 4096; idx += 256) {
      int a = idx >> 6, mm = idx & 63;
      Us[a][mm] = U_W[(size_t)(r * 64 + a) * 64 + mm];
      Tb[a][mm] = Tbuf[(((size_t)r * NOUT + o) * 64 + a) * 64 + mm];
    }
    __syncthreads();
    for (int mm = 0; mm < 64; ++mm) {
      float av[4], bv[4];
#pragma unroll
      for (int i = 0; i < 4; ++i) av[i] = Us[ty * 4 + i][mm];
#pragma unroll
      for (int j = 0; j < 4; ++j) bv[j] = Tb[mm][tx * 4 + j];
#pragma unroll
      for (int i = 0; i < 4; ++i)
#pragma unroll
        for (int j = 0; j < 4; ++j) acc[i][j] = fmaf(av[i], bv[j], acc[i][j]);
    }
    __syncthreads();
  }
#pragma unroll
  for (int i = 0; i < 4; ++i)
#pragma unroll
    for (int j = 0; j < 4; ++j) Q[ty * 4 + i][tx * 4 + j] = acc[i][j];
  __syncthreads();
  // pack coefficients: B[k][col] for k = 8*g4+e within chunk c, col = o
  int ot = o >> 4, o15 = o & 15;
  for (int idx = tid; idx < NGRP * 8; idx += 256) {
    int g = idx >> 3, e = idx & 7;
    int2 ml = gtab[g];
    int m = ml.x, l = ml.y + e;
    float v;
    if (l < 64) v = (m == l) ? Q[m][m] : Q[m][l] + Q[l][m];
    else if (l == 64) v = (m == 64) ? (cbuf[o] + b_out[o]) : linbuf[o * 64 + m];
    else v = 0.f;
    int c = g >> 2, g4 = g & 3;
    Bfrag[((((size_t)c * 3 + ot) * 64) + g4 * 16 + o15) * 8 + e] = f2bf(v);
  }
}

// ---------------- logits via MFMA: P(N x 2400) @ C(2400 x 48), A generated on the fly ----------------
__global__ __launch_bounds__(256) void k_logits(const ushort* __restrict__ hbf,
                                                const ushort* __restrict__ Bfrag,
                                                const int2* __restrict__ gtab,
                                                float* __restrict__ logits, int N) {
  __shared__ float eh[128][77];
  __shared__ int2 gs[NGRP];
  int tid = threadIdx.x;
  int n0 = blockIdx.x * 128;
  // stage h tile (bf16 -> fp32), extended with [64]=1, [65..76]=0
  for (int idx = tid; idx < 128 * 16; idx += 256) {
    int n = idx >> 4, f4 = (idx & 15) << 2;
    int gn = n0 + n;
    float v0 = 0.f, v1 = 0.f, v2 = 0.f, v3 = 0.f;
    if (gn < N) {
      ushort4 u = *(const ushort4*)&hbf[(size_t)gn * HD + f4];
      v0 = bf2f(u.x); v1 = bf2f(u.y); v2 = bf2f(u.z); v3 = bf2f(u.w);
    }
    eh[n][f4] = v0; eh[n][f4 + 1] = v1; eh[n][f4 + 2] = v2; eh[n][f4 + 3] = v3;
  }
  for (int idx = tid; idx < 128 * 13; idx += 256) {
    int n = idx / 13, j = idx - n * 13;
    eh[n][64 + j] = (j == 0) ? 1.f : 0.f;
  }
  for (int idx = tid; idx < NGRP; idx += 256) gs[idx] = gtab[idx];
  __syncthreads();

  int w = tid >> 6, lane = tid & 63;
  int g4 = lane >> 4, c15 = lane & 15;
  float4v acc[2][3];
#pragma unroll
  for (int t = 0; t < 2; ++t)
#pragma unroll
    for (int ot = 0; ot < 3; ++ot) acc[t][ot] = (float4v){0.f, 0.f, 0.f, 0.f};
  const float* ehr0 = &eh[(w * 2 + 0) * 16 + c15][0];
  const float* ehr1 = &eh[(w * 2 + 1) * 16 + c15][0];

  for (int c = 0; c < NCHUNK; ++c) {
    const short8v b0 = *(const short8v*)&Bfrag[(((size_t)c * 3 + 0) * 64 + lane) * 8];
    const short8v b1 = *(const short8v*)&Bfrag[(((size_t)c * 3 + 1) * 64 + lane) * 8];
    const short8v b2 = *(const short8v*)&Bfrag[(((size_t)c * 3 + 2) * 64 + lane) * 8];
    int2 ml = gs[c * 4 + g4];
    int m = ml.x, l0 = ml.y;
    float hm0 = ehr0[m], hm1 = ehr1[m];
    short8v a0, a1;
#pragma unroll
    for (int e = 0; e < 8; ++e) {
      a0[e] = (short)f2bf(hm0 * ehr0[l0 + e]);
      a1[e] = (short)f2bf(hm1 * ehr1[l0 + e]);
    }
    acc[0][0] = __builtin_amdgcn_mfma_f32_16x16x32_bf16(a0, b0, acc[0][0], 0, 0, 0);
    acc[1][0] = __builtin_amdgcn_mfma_f32_16x16x32_bf16(a1, b0, acc[1][0], 0, 0, 0);
    acc[0][1] = __builtin_amdgcn_mfma_f32_16x16x32_bf16(a0, b1, acc[0][1], 0, 0, 0);
    acc[1][1] = __builtin_amdgcn_mfma_f32_16x16x32_bf16(a1, b1, acc[1][1], 0, 0, 0);
    acc[0][2] = __builtin_amdgcn_mfma_f32_16x16x32_bf16(a0, b2, acc[0][2], 0, 0, 0);
    acc[1][2] = __builtin_amdgcn_mfma_f32_16x16x32_bf16(a1, b2, acc[1][2], 0, 0, 0);
  }

  // C/D layout: col = lane&15, row = (lane>>4)*4 + reg  [verified m89/m91]
#pragma unroll
  for (int t = 0; t < 2; ++t) {
    int nbase = n0 + (w * 2 + t) * 16 + g4 * 4;
#pragma unroll
    for (int ot = 0; ot < 3; ++ot) {
      int o = ot * 16 + c15;
      if (o < NOUT) {
#pragma unroll
        for (int r = 0; r < 4; ++r) {
          int n = nbase + r;
          if (n < N) logits[(size_t)n * NOUT + o] = acc[t][ot][r];
        }
      }
    }
  }
}

// ---------------- expmap0 + proj + log_softmax ----------------
__global__ __launch_bounds__(256) void k_epi(const float* __restrict__ logits, float* __restrict__ out, int N) {
  int n = blockIdx.x * 256 + threadIdx.x;
  if (n >= N) return;
  float v[40];
  const float4* p = (const float4*)(logits + (size_t)n * NOUT);
#pragma unroll
  for (int i = 0; i < 10; ++i) {
    float4 t = p[i];
    v[4 * i] = t.x; v[4 * i + 1] = t.y; v[4 * i + 2] = t.z; v[4 * i + 3] = t.w;
  }
  float s = 0.f;
#pragma unroll
  for (int i = 0; i < 40; ++i) s = fmaf(v[i], v[i], s);
  float norm = sqrtf(s);
  float un = fmaxf(norm, 1e-15f);
  float sc = tanhf(un) / un;
  float s2 = 0.f;
#pragma unroll
  for (int i = 0; i < 40; ++i) { v[i] *= sc; s2 = fmaf(v[i], v[i], s2); }
  float ny = fmaxf(sqrtf(s2), 1e-15f);
  float maxn = 1.0f - 4e-3f;
  if (ny > maxn) {
    float f = maxn / ny;
#pragma unroll
    for (int i = 0; i < 40; ++i) v[i] *= f;
  }
  float vmax = v[0];
#pragma unroll
  for (int i = 1; i < 40; ++i) vmax = fmaxf(vmax, v[i]);
  float se = 0.f;
#pragma unroll
  for (int i = 0; i < 40; ++i) se += expf(v[i] - vmax);
  float lse = logf(se);
  float4* q = (float4*)(out + (size_t)n * NOUT);
#pragma unroll
  for (int i = 0; i < 10; ++i) {
    float4 t;
    t.x = v[4 * i] - vmax - lse;
    t.y = v[4 * i + 1] - vmax - lse;
    t.z = v[4 * i + 2] - vmax - lse;
    t.w = v[4 * i + 3] - vmax - lse;
    q[i] = t;
  }
}

extern "C" void kernel_launch(void* const* d_in, const int* in_sizes, int n_in,
                              void* d_out, int out_size, void* d_ws, size_t ws_size,
                              hipStream_t stream) {
  const float* x = (const float*)d_in[0];
  const int* erow = (const int*)d_in[1];
  const int* ecol = (const int*)d_in[2];
  const float* ew = (const float*)d_in[3];
  const float* W_in = (const float*)d_in[4];
  const float* b_in = (const float*)d_in[5];
  const float* conv_W = (const float*)d_in[6];
  const float* U_W = (const float*)d_in[7];
  const float* U_b = (const float*)d_in[8];
  const float* V_W = (const float*)d_in[9];
  const float* V_b = (const float*)d_in[10];
  const float* W_out = (const float*)d_in[11];
  const float* b_out = (const float*)d_in[12];
  int N = in_sizes[0] / F_IN;
  int E = in_sizes[1];
  float* out = (float*)d_out;

  char* base = (char*)d_ws;
  size_t off = 0;
  auto alloc = [&](size_t bytes) -> void* {
    void* p = base + off;
    off += (bytes + 255) & ~(size_t)255;
    return p;
  };
  float* h0 = (float*)alloc((size_t)N * HD * 4);
  ushort* h0bf = (ushort*)alloc((size_t)N * HD * 2);
  ushort* hbfA = (ushort*)alloc((size_t)N * HD * 2);
  ushort* hbfB = (ushort*)alloc((size_t)N * HD * 2);
  float* logits = (float*)alloc((size_t)N * NOUT * 4);
  int* rowptr = (int*)alloc((size_t)(N + 1) * 4);
  int* cursor = (int*)alloc((size_t)N * 4);
  int* counts = (int*)alloc((size_t)N * 4);
  int2* colw = (int2*)alloc((size_t)E * 8);
  float* Tbuf = (float*)alloc((size_t)NRANK * NOUT * 64 * 64 * 4);
  ushort* Bfrag = (ushort*)alloc((size_t)NCHUNK * 3 * 64 * 8 * 2);
  float* linbuf = (float*)alloc(NOUT * 64 * 4);
  float* cbuf = (float*)alloc(NOUT * 4);
  int2* gtab = (int2*)alloc(NGRP * 8);
  int* bsum = (int*)alloc(64 * 4);
  int* boff = (int*)alloc(64 * 4);

  int G = (N + 1023) / 1024;

  k_zero<<<(N + 255) / 256, 256, 0, stream>>>(counts, linbuf, cbuf, (ushort4*)Bfrag, N);
  k_count<<<(E + 255) / 256, 256, 0, stream>>>(erow, counts, E);
  k_scan1<<<G, 1024, 0, stream>>>(counts, rowptr, bsum, N);
  k_scan2<<<1, 64, 0, stream>>>(bsum, boff, G);
  k_scan3<<<G, 1024, 0, stream>>>(rowptr, cursor, boff, N, E);
  k_fill<<<(E + 255) / 256, 256, 0, stream>>>(erow, ecol, ew, cursor, colw, E);
  k_gemm_in<<<(N + 63) / 64, 256, 0, stream>>>(x, W_in, b_in, h0, h0bf, N);
  k_gtab<<<1, 512, 0, stream>>>(gtab);
  k_T<<<NRANK * NOUT, 256, 0, stream>>>(W_out, V_W, V_b, U_W, U_b, Tbuf, linbuf, cbuf);
  k_Q<<<NOUT, 256, 0, stream>>>(U_W, Tbuf, linbuf, cbuf, b_out, gtab, Bfrag);

  const ushort* hin = h0bf;
  ushort* hout = hbfA;
  for (int l = 0; l < NL; ++l) {
    float beta = (float)std::log(0.5 / (double)(l + 1) + 1.0);
    k_layer<<<(N + 3) / 4, 256, 0, stream>>>(hin, h0, rowptr, colw, conv_W + (size_t)l * HD * HD,
                                             beta, hout, N);
    hin = hout;
    hout = (hout == hbfA) ? hbfB : hbfA;
  }
  k_logits<<<(N + 127) / 128, 256, 0, stream>>>(hin, Bfrag, gtab, logits, N);
  k_epi<<<(N + 255) / 256, 256, 0, stream>>>(logits, out, N);
}

// Round 3
// 630.737 us; speedup vs baseline: 2.2138x; 1.6881x over previous
//
#include <hip/hip_runtime.h>
#include <cmath>

#define F_IN 500
#define HD 64
#define NL 8
#define NRANK 3
#define NOUT 40
#define NGRP 300   // 297 real (m,l0) groups of 8 + 3 zero pads -> K = 2400
#define NCHUNK 75  // 2400 / 32
#define RPW 2      // rows per wave in k_layer

typedef __attribute__((ext_vector_type(8))) short short8v;
typedef __attribute__((ext_vector_type(4))) float float4v;

__device__ __forceinline__ float bf2f(ushort u) {
  union { unsigned int i; float f; } v;
  v.i = ((unsigned int)u) << 16;
  return v.f;
}
__device__ __forceinline__ ushort f2bf(float f) {
  union { float f; unsigned int i; } v;
  v.f = f;
  unsigned int b = v.i;
  return (ushort)((b + 0x7FFFu + ((b >> 16) & 1u)) >> 16);
}

// ---------------- zero init ----------------
__global__ __launch_bounds__(256) void k_zero(int* counts, float* linbuf, float* cbuf,
                                              ushort4* bfrag4, int N) {
  int i = blockIdx.x * 256 + threadIdx.x;
  if (i < N) counts[i] = 0;
  if (i < NOUT * HD) linbuf[i] = 0.f;
  if (i < NOUT) cbuf[i] = 0.f;
  if (i < NCHUNK * 3 * 64 * 2) bfrag4[i] = make_ushort4(0, 0, 0, 0);
}

__global__ __launch_bounds__(256) void k_count(const int* __restrict__ row, int* counts, int E) {
  int e = blockIdx.x * 256 + threadIdx.x;
  if (e < E) atomicAdd(&counts[row[e]], 1);
}

// ---------------- parallel scan (3 kernels) ----------------
__global__ __launch_bounds__(1024) void k_scan1(const int* __restrict__ counts, int* __restrict__ rowptr,
                                                int* __restrict__ bsum, int N) {
  __shared__ int sh[1024];
  int t = threadIdx.x, i = blockIdx.x * 1024 + t;
  int c = (i < N) ? counts[i] : 0;
  sh[t] = c;
  __syncthreads();
  for (int d = 1; d < 1024; d <<= 1) {
    int v = (t >= d) ? sh[t - d] : 0;
    __syncthreads();
    sh[t] += v;
    __syncthreads();
  }
  if (i < N) rowptr[i] = sh[t] - c;  // block-local exclusive
  if (t == 1023) bsum[blockIdx.x] = sh[1023];
}

__global__ __launch_bounds__(64) void k_scan2(const int* __restrict__ bsum, int* __restrict__ boff, int G) {
  int t = threadIdx.x;
  int base = 0;
  for (int s = 0; s < G; s += 64) {
    int i = s + t;
    int v = (i < G) ? bsum[i] : 0;
    int orig = v;
    for (int d = 1; d < 64; d <<= 1) {
      int u = __shfl_up(v, d, 64);
      if (t >= d) v += u;
    }
    if (i < G) boff[i] = base + v - orig;
    base += __shfl(v, 63, 64);
  }
}

__global__ __launch_bounds__(1024) void k_scan3(int* __restrict__ rowptr, int* __restrict__ cursor,
                                                const int* __restrict__ boff, int N, int E) {
  int i = blockIdx.x * 1024 + threadIdx.x;
  if (i < N) {
    int v = rowptr[i] + boff[blockIdx.x];
    rowptr[i] = v;
    cursor[i] = v;
  }
  if (i == 0) rowptr[N] = E;
}

__global__ __launch_bounds__(256) void k_fill(const int* __restrict__ row, const int* __restrict__ col,
                                              const float* __restrict__ w, int* cursor,
                                              int2* __restrict__ colw, int E) {
  int e = blockIdx.x * 256 + threadIdx.x;
  if (e < E) {
    int r = row[e];
    int p = atomicAdd(&cursor[r], 1);
    colw[p] = make_int2(col[e], __float_as_int(w[e]));
  }
}

// ---------------- W_in -> bf16 [64 cols][512 k], zero-padded ----------------
__global__ __launch_bounds__(256) void k_wcvt(const float* __restrict__ W, ushort* __restrict__ Wbf) {
  int i = blockIdx.x * 256 + threadIdx.x;
  if (i >= 64 * 512) return;
  int d = i >> 9, k = i & 511;
  Wbf[i] = (k < F_IN) ? f2bf(W[(size_t)k * HD + d]) : (ushort)0;
}

// ---------------- input GEMM via MFMA: h0 = relu(x @ W_in + b), bf16 ----------------
__global__ __launch_bounds__(256) void k_gemm_in(const float* __restrict__ x,
                                                 const ushort* __restrict__ Wbf,
                                                 const float* __restrict__ b,
                                                 ushort* __restrict__ h0bf, int N) {
  int tid = threadIdx.x;
  int w = tid >> 6, lane = tid & 63;
  int c15 = lane & 15, g4 = lane >> 4;
  int rowA = blockIdx.x * 64 + w * 16 + c15;
  if (rowA >= N) rowA = N - 1;  // clamp; results discarded at store
  const float* xr = x + (size_t)rowA * F_IN;
  int koff = g4 * 8;
  float4v acc[4];
#pragma unroll
  for (int ct = 0; ct < 4; ++ct) acc[ct] = (float4v){0.f, 0.f, 0.f, 0.f};
  for (int kc = 0; kc < 16; ++kc) {
    int kbase = kc * 32 + koff;
    short8v a;
    if (kc < 15) {
      float4 f0 = *(const float4*)(xr + kbase);
      float4 f1 = *(const float4*)(xr + kbase + 4);
      a[0] = (short)f2bf(f0.x); a[1] = (short)f2bf(f0.y);
      a[2] = (short)f2bf(f0.z); a[3] = (short)f2bf(f0.w);
      a[4] = (short)f2bf(f1.x); a[5] = (short)f2bf(f1.y);
      a[6] = (short)f2bf(f1.z); a[7] = (short)f2bf(f1.w);
    } else {
#pragma unroll
      for (int e = 0; e < 8; ++e) {
        int k = kbase + e;
        a[e] = (short)(k < F_IN ? f2bf(xr[k]) : (ushort)0);
      }
    }
#pragma unroll
    for (int ct = 0; ct < 4; ++ct) {
      const short8v bb = *(const short8v*)&Wbf[((ct * 16 + c15) << 9) + kbase];
      acc[ct] = __builtin_amdgcn_mfma_f32_16x16x32_bf16(a, bb, acc[ct], 0, 0, 0);
    }
  }
  int mbase = blockIdx.x * 64 + w * 16 + g4 * 4;
#pragma unroll
  for (int ct = 0; ct < 4; ++ct) {
    int d = ct * 16 + c15;
    float bias = b[d];
#pragma unroll
    for (int r = 0; r < 4; ++r) {
      int m = mbase + r;
      if (m < N) {
        float v = acc[ct][r] + bias;
        h0bf[(size_t)m * HD + d] = f2bf(fmaxf(v, 0.f));
      }
    }
  }
}

// ---------------- GCN2 layer: CSR SpMM (bf16, unroll-4) + fused identity matvec ----------------
__global__ __launch_bounds__(256) void k_layer(const ushort* __restrict__ hin,
                                               const ushort* __restrict__ h0bf,
                                               const int* __restrict__ rowptr, const int2* __restrict__ colw,
                                               const float* __restrict__ convW, float beta,
                                               ushort* __restrict__ hout, int N) {
  __shared__ float Ml[64][64];          // (1-b)I + b*W
  __shared__ float sup[4][RPW][64];
  int tid = threadIdx.x, wv = tid >> 6, t = tid & 63;
  for (int idx = tid; idx < 4096; idx += 256) {
    int i = idx >> 6, j = idx & 63;
    Ml[i][j] = beta * convW[idx] + ((i == j) ? (1.f - beta) : 0.f);
  }
  __syncthreads();
  int nb = blockIdx.x * 4 * RPW + wv * RPW;
  for (int rr = 0; rr < RPW; ++rr) {
    int n = nb + rr;
    if (n >= N) break;
    int e0 = rowptr[n], e1 = rowptr[n + 1];
    float a0 = 0.f, a1 = 0.f, a2 = 0.f, a3 = 0.f;
    int e = e0;
    for (; e + 4 <= e1; e += 4) {
      int2 c0 = colw[e], c1 = colw[e + 1], c2 = colw[e + 2], c3 = colw[e + 3];
      float g0 = bf2f(hin[(size_t)c0.x * HD + t]);
      float g1 = bf2f(hin[(size_t)c1.x * HD + t]);
      float g2 = bf2f(hin[(size_t)c2.x * HD + t]);
      float g3 = bf2f(hin[(size_t)c3.x * HD + t]);
      a0 = fmaf(__int_as_float(c0.y), g0, a0);
      a1 = fmaf(__int_as_float(c1.y), g1, a1);
      a2 = fmaf(__int_as_float(c2.y), g2, a2);
      a3 = fmaf(__int_as_float(c3.y), g3, a3);
    }
    for (; e < e1; ++e) {
      int2 c = colw[e];
      a0 = fmaf(__int_as_float(c.y), bf2f(hin[(size_t)c.x * HD + t]), a0);
    }
    sup[wv][rr][t] = 0.9f * ((a0 + a1) + (a2 + a3)) + 0.1f * bf2f(h0bf[(size_t)n * HD + t]);
  }
  // matvec: same wave reads its own sup -> no block barrier needed
  for (int rr = 0; rr < RPW; ++rr) {
    int n = nb + rr;
    if (n >= N) break;
    float mv = 0.f;
#pragma unroll
    for (int h = 0; h < 64; ++h) mv = fmaf(sup[wv][rr][h], Ml[h][t], mv);
    hout[(size_t)n * HD + t] = f2bf(fmaxf(mv, 0.f));
  }
}

// ---------------- group table: g -> (m, l0) ----------------
__global__ __launch_bounds__(512) void k_gtab(int2* __restrict__ gtab) {
  int g = threadIdx.x;
  if (g >= NGRP) return;
  int m = 64, l0 = 65;
  if (g < 297) {
    int cum = 0;
    for (int mm = 0; mm < 65; ++mm) {
      int ng = (65 - mm + 7) >> 3;
      if (g < cum + ng) { m = mm; l0 = mm + (g - cum) * 8; break; }
      cum += ng;
    }
  }
  gtab[g] = make_int2(m, l0);
}

// ---------------- T[r,o] = Wo_o @ V_r^T  (+ linear/const bias terms) ----------------
__global__ __launch_bounds__(256) void k_T(const float* __restrict__ W_out, const float* __restrict__ V_W,
                                           const float* __restrict__ V_b, const float* __restrict__ U_W,
                                           const float* __restrict__ U_b,
                                           float* __restrict__ Tbuf, float* linbuf, float* cbuf) {
  int o = blockIdx.x % NOUT;
  int r = blockIdx.x / NOUT;
  __shared__ float Wo[64][65];
  __shared__ float Vs[64][65];
  __shared__ float t1[64], t2[64];
  int tid = threadIdx.x;
  int tx = tid & 15, ty = tid >> 4;
  for (int idx = tid; idx < 4096; idx += 256) {
    int m = idx >> 6, l = idx & 63;
    Wo[m][l] = W_out[(size_t)idx * NOUT + o];
    Vs[m][l] = V_W[(size_t)(r * 64 + m) * 64 + l];
  }
  __syncthreads();
  float acc[4][4] = {};
  for (int l = 0; l < 64; ++l) {
    float av[4], bv[4];
#pragma unroll
    for (int i = 0; i < 4; ++i) av[i] = Wo[ty * 4 + i][l];
#pragma unroll
    for (int j = 0; j < 4; ++j) bv[j] = Vs[tx * 4 + j][l];
#pragma unroll
    for (int i = 0; i < 4; ++i)
#pragma unroll
      for (int j = 0; j < 4; ++j) acc[i][j] = fmaf(av[i], bv[j], acc[i][j]);
  }
#pragma unroll
  for (int i = 0; i < 4; ++i)
#pragma unroll
    for (int j = 0; j < 4; ++j)
      Tbuf[(((size_t)r * NOUT + o) * 64 + ty * 4 + i) * 64 + tx * 4 + j] = acc[i][j];
  if (tid < 64) {
    float s1 = 0.f, s2 = 0.f;
    for (int l = 0; l < 64; ++l) s1 = fmaf(Wo[tid][l], V_b[r * 64 + l], s1);
    for (int m = 0; m < 64; ++m) s2 = fmaf(Wo[m][tid], U_b[r * 64 + m], s2);
    t1[tid] = s1;
    t2[tid] = s2;
  }
  __syncthreads();
  if (tid < 64) {
    float s = 0.f, s2 = 0.f;
    for (int m = 0; m < 64; ++m) s = fmaf(U_W[(size_t)(r * 64 + tid) * 64 + m], t1[m], s);
    for (int l = 0; l < 64; ++l) s2 = fmaf(Vs[tid][l], t2[l], s2);
    atomicAdd(&linbuf[o * 64 + tid], s + s2);
  }
  if (tid == 0) {
    float s = 0.f;
    for (int m = 0; m < 64; ++m) s = fmaf(U_b[r * 64 + m], t1[m], s);
    atomicAdd(&cbuf[o], s);
  }
}

// ---------------- Q_o = sum_r U_r @ T[r,o]; pack bf16 B-fragments ----------------
__global__ __launch_bounds__(256) void k_Q(const float* __restrict__ U_W, const float* __restrict__ Tbuf,
                                           const float* __restrict__ linbuf, const float* __restrict__ cbuf,
                                           const float* __restrict__ b_out,
                                           const int2* __restrict__ gtab, ushort* __restrict__ Bfrag) {
  int o = blockIdx.x;
  __shared__ float Us[64][65];
  __shared__ float Tb[64][65];
  __shared__ float Q[64][65];
  int tid = threadIdx.x, tx = tid & 15, ty = tid >> 4;
  float acc[4][4] = {};
  for (int r = 0; r < NRANK; ++r) {
    for (int idx = tid; idx < 4096; idx += 256) {
      int a = idx >> 6, mm = idx & 63;
      Us[a][mm] = U_W[(size_t)(r * 64 + a) * 64 + mm];
      Tb[a][mm] = Tbuf[(((size_t)r * NOUT + o) * 64 + a) * 64 + mm];
    }
    __syncthreads();
    for (int mm = 0; mm < 64; ++mm) {
      float av[4], bv[4];
#pragma unroll
      for (int i = 0; i < 4; ++i) av[i] = Us[ty * 4 + i][mm];
#pragma unroll
      for (int j = 0; j < 4; ++j) bv[j] = Tb[mm][tx * 4 + j];
#pragma unroll
      for (int i = 0; i < 4; ++i)
#pragma unroll
        for (int j = 0; j < 4; ++j) acc[i][j] = fmaf(av[i], bv[j], acc[i][j]);
    }
    __syncthreads();
  }
#pragma unroll
  for (int i = 0; i < 4; ++i)
#pragma unroll
    for (int j = 0; j < 4; ++j) Q[ty * 4 + i][tx * 4 + j] = acc[i][j];
  __syncthreads();
  int ot = o >> 4, o15 = o & 15;
  for (int idx = tid; idx < NGRP * 8; idx += 256) {
    int g = idx >> 3, e = idx & 7;
    int2 ml = gtab[g];
    int m = ml.x, l = ml.y + e;
    float v;
    if (l < 64) v = (m == l) ? Q[m][m] : Q[m][l] + Q[l][m];
    else if (l == 64) v = (m == 64) ? (cbuf[o] + b_out[o]) : linbuf[o * 64 + m];
    else v = 0.f;
    int c = g >> 2, g4 = g & 3;
    Bfrag[((((size_t)c * 3 + ot) * 64) + g4 * 16 + o15) * 8 + e] = f2bf(v);
  }
}

// ---------------- logits via MFMA + fused expmap0/proj/log_softmax ----------------
__global__ __launch_bounds__(256) void k_logits(const ushort* __restrict__ hbf,
                                                const ushort* __restrict__ Bfrag,
                                                const int2* __restrict__ gtab,
                                                float* __restrict__ out, int N) {
  __shared__ float eh[128][77];
  __shared__ int2 gs[NGRP];
  int tid = threadIdx.x;
  int n0 = blockIdx.x * 128;
  for (int idx = tid; idx < 128 * 16; idx += 256) {
    int n = idx >> 4, f4 = (idx & 15) << 2;
    int gn = n0 + n;
    float v0 = 0.f, v1 = 0.f, v2 = 0.f, v3 = 0.f;
    if (gn < N) {
      ushort4 u = *(const ushort4*)&hbf[(size_t)gn * HD + f4];
      v0 = bf2f(u.x); v1 = bf2f(u.y); v2 = bf2f(u.z); v3 = bf2f(u.w);
    }
    eh[n][f4] = v0; eh[n][f4 + 1] = v1; eh[n][f4 + 2] = v2; eh[n][f4 + 3] = v3;
  }
  for (int idx = tid; idx < 128 * 13; idx += 256) {
    int n = idx / 13, j = idx - n * 13;
    eh[n][64 + j] = (j == 0) ? 1.f : 0.f;
  }
  for (int idx = tid; idx < NGRP; idx += 256) gs[idx] = gtab[idx];
  __syncthreads();

  int w = tid >> 6, lane = tid & 63;
  int g4 = lane >> 4, c15 = lane & 15;
  float4v acc[2][3];
#pragma unroll
  for (int t = 0; t < 2; ++t)
#pragma unroll
    for (int ot = 0; ot < 3; ++ot) acc[t][ot] = (float4v){0.f, 0.f, 0.f, 0.f};
  const float* ehr0 = &eh[(w * 2 + 0) * 16 + c15][0];
  const float* ehr1 = &eh[(w * 2 + 1) * 16 + c15][0];

  for (int c = 0; c < NCHUNK; ++c) {
    const short8v b0 = *(const short8v*)&Bfrag[(((size_t)c * 3 + 0) * 64 + lane) * 8];
    const short8v b1 = *(const short8v*)&Bfrag[(((size_t)c * 3 + 1) * 64 + lane) * 8];
    const short8v b2 = *(const short8v*)&Bfrag[(((size_t)c * 3 + 2) * 64 + lane) * 8];
    int2 ml = gs[c * 4 + g4];
    int m = ml.x, l0 = ml.y;
    float hm0 = ehr0[m], hm1 = ehr1[m];
    short8v a0, a1;
#pragma unroll
    for (int e = 0; e < 8; ++e) {
      a0[e] = (short)f2bf(hm0 * ehr0[l0 + e]);
      a1[e] = (short)f2bf(hm1 * ehr1[l0 + e]);
    }
    acc[0][0] = __builtin_amdgcn_mfma_f32_16x16x32_bf16(a0, b0, acc[0][0], 0, 0, 0);
    acc[1][0] = __builtin_amdgcn_mfma_f32_16x16x32_bf16(a1, b0, acc[1][0], 0, 0, 0);
    acc[0][1] = __builtin_amdgcn_mfma_f32_16x16x32_bf16(a0, b1, acc[0][1], 0, 0, 0);
    acc[1][1] = __builtin_amdgcn_mfma_f32_16x16x32_bf16(a1, b1, acc[1][1], 0, 0, 0);
    acc[0][2] = __builtin_amdgcn_mfma_f32_16x16x32_bf16(a0, b2, acc[0][2], 0, 0, 0);
    acc[1][2] = __builtin_amdgcn_mfma_f32_16x16x32_bf16(a1, b2, acc[1][2], 0, 0, 0);
  }

  __syncthreads();  // all eh reads done; reuse as logits tile [128][41]
  float* ls = &eh[0][0];
#pragma unroll
  for (int t = 0; t < 2; ++t) {
    int rbase = (w * 2 + t) * 16 + g4 * 4;
#pragma unroll
    for (int ot = 0; ot < 3; ++ot) {
      int o = ot * 16 + c15;
      if (o < NOUT) {
#pragma unroll
        for (int r = 0; r < 4; ++r) ls[(rbase + r) * 41 + o] = acc[t][ot][r];
      }
    }
  }
  __syncthreads();
  if (tid < 128) {
    int n = n0 + tid;
    if (n < N) {
      float v[40];
      float s = 0.f;
#pragma unroll
      for (int i = 0; i < 40; ++i) { v[i] = ls[tid * 41 + i]; s = fmaf(v[i], v[i], s); }
      float un = fmaxf(sqrtf(s), 1e-15f);
      float sc = tanhf(un) / un;
      float s2 = 0.f;
#pragma unroll
      for (int i = 0; i < 40; ++i) { v[i] *= sc; s2 = fmaf(v[i], v[i], s2); }
      float ny = fmaxf(sqrtf(s2), 1e-15f);
      float maxn = 1.0f - 4e-3f;
      if (ny > maxn) {
        float f = maxn / ny;
#pragma unroll
        for (int i = 0; i < 40; ++i) v[i] *= f;
      }
      float vmax = v[0];
#pragma unroll
      for (int i = 1; i < 40; ++i) vmax = fmaxf(vmax, v[i]);
      float se = 0.f;
#pragma unroll
      for (int i = 0; i < 40; ++i) se += expf(v[i] - vmax);
      float lse = logf(se) + vmax;
      float4* q = (float4*)(out + (size_t)n * NOUT);
#pragma unroll
      for (int i = 0; i < 10; ++i) {
        float4 t;
        t.x = v[4 * i] - lse;
        t.y = v[4 * i + 1] - lse;
        t.z = v[4 * i + 2] - lse;
        t.w = v[4 * i + 3] - lse;
        q[i] = t;
      }
    }
  }
}

extern "C" void kernel_launch(void* const* d_in, const int* in_sizes, int n_in,
                              void* d_out, int out_size, void* d_ws, size_t ws_size,
                              hipStream_t stream) {
  const float* x = (const float*)d_in[0];
  const int* erow = (const int*)d_in[1];
  const int* ecol = (const int*)d_in[2];
  const float* ew = (const float*)d_in[3];
  const float* W_in = (const float*)d_in[4];
  const float* b_in = (const float*)d_in[5];
  const float* conv_W = (const float*)d_in[6];
  const float* U_W = (const float*)d_in[7];
  const float* U_b = (const float*)d_in[8];
  const float* V_W = (const float*)d_in[9];
  const float* V_b = (const float*)d_in[10];
  const float* W_out = (const float*)d_in[11];
  const float* b_out = (const float*)d_in[12];
  int N = in_sizes[0] / F_IN;
  int E = in_sizes[1];
  float* out = (float*)d_out;

  char* base = (char*)d_ws;
  size_t off = 0;
  auto alloc = [&](size_t bytes) -> void* {
    void* p = base + off;
    off += (bytes + 255) & ~(size_t)255;
    return p;
  };
  ushort* h0bf = (ushort*)alloc((size_t)N * HD * 2);
  ushort* hbfA = (ushort*)alloc((size_t)N * HD * 2);
  ushort* hbfB = (ushort*)alloc((size_t)N * HD * 2);
  int* rowptr = (int*)alloc((size_t)(N + 1) * 4);
  int* cursor = (int*)alloc((size_t)N * 4);
  int* counts = (int*)alloc((size_t)N * 4);
  int2* colw = (int2*)alloc((size_t)E * 8);
  float* Tbuf = (float*)alloc((size_t)NRANK * NOUT * 64 * 64 * 4);
  ushort* Bfrag = (ushort*)alloc((size_t)NCHUNK * 3 * 64 * 8 * 2);
  ushort* Wbf = (ushort*)alloc((size_t)64 * 512 * 2);
  float* linbuf = (float*)alloc(NOUT * 64 * 4);
  float* cbuf = (float*)alloc(NOUT * 4);
  int2* gtab = (int2*)alloc(NGRP * 8);
  int* bsum = (int*)alloc(64 * 4);
  int* boff = (int*)alloc(64 * 4);

  int G = (N + 1023) / 1024;

  k_zero<<<(N + 255) / 256, 256, 0, stream>>>(counts, linbuf, cbuf, (ushort4*)Bfrag, N);
  k_count<<<(E + 255) / 256, 256, 0, stream>>>(erow, counts, E);
  k_scan1<<<G, 1024, 0, stream>>>(counts, rowptr, bsum, N);
  k_scan2<<<1, 64, 0, stream>>>(bsum, boff, G);
  k_scan3<<<G, 1024, 0, stream>>>(rowptr, cursor, boff, N, E);
  k_fill<<<(E + 255) / 256, 256, 0, stream>>>(erow, ecol, ew, cursor, colw, E);
  k_wcvt<<<128, 256, 0, stream>>>(W_in, Wbf);
  k_gemm_in<<<(N + 63) / 64, 256, 0, stream>>>(x, Wbf, b_in, h0bf, N);
  k_gtab<<<1, 512, 0, stream>>>(gtab);
  k_T<<<NRANK * NOUT, 256, 0, stream>>>(W_out, V_W, V_b, U_W, U_b, Tbuf, linbuf, cbuf);
  k_Q<<<NOUT, 256, 0, stream>>>(U_W, Tbuf, linbuf, cbuf, b_out, gtab, Bfrag);

  const ushort* hin = h0bf;
  ushort* hout = hbfA;
  for (int l = 0; l < NL; ++l) {
    float beta = (float)std::log(0.5 / (double)(l + 1) + 1.0);
    k_layer<<<(N + 4 * RPW - 1) / (4 * RPW), 256, 0, stream>>>(hin, h0bf, rowptr, colw,
                                                               conv_W + (size_t)l * HD * HD,
                                                               beta, hout, N);
    hin = hout;
    hout = (hout == hbfA) ? hbfB : hbfA;
  }
  k_logits<<<(N + 127) / 128, 256, 0, stream>>>(hin, Bfrag, gtab, out, N);
}

// Round 4
// 501.940 us; speedup vs baseline: 2.7818x; 1.2566x over previous
//
#include <hip/hip_runtime.h>
#include <cmath>

#define F_IN 500
#define HD 64
#define NL 8
#define NRANK 3
#define NOUT 40
#define NGRP 300   // 297 real (m,l0) groups of 8 + 3 zero pads -> K = 2400
#define NCHUNK 75  // 2400 / 32

typedef __attribute__((ext_vector_type(8))) short short8v;
typedef __attribute__((ext_vector_type(4))) float float4v;

__device__ __forceinline__ float bf2f(ushort u) {
  union { unsigned int i; float f; } v;
  v.i = ((unsigned int)u) << 16;
  return v.f;
}
__device__ __forceinline__ ushort f2bf(float f) {
  union { float f; unsigned int i; } v;
  v.f = f;
  unsigned int b = v.i;
  return (ushort)((b + 0x7FFFu + ((b >> 16) & 1u)) >> 16);
}

// ---------------- zero init ----------------
__global__ __launch_bounds__(256) void k_zero(int* counts, float* linbuf, float* cbuf,
                                              ushort4* bfrag4, int N) {
  int i = blockIdx.x * 256 + threadIdx.x;
  if (i < N) counts[i] = 0;
  if (i < NOUT * HD) linbuf[i] = 0.f;
  if (i < NOUT) cbuf[i] = 0.f;
  if (i < NCHUNK * 3 * 64 * 2) bfrag4[i] = make_ushort4(0, 0, 0, 0);
}

__global__ __launch_bounds__(256) void k_count(const int* __restrict__ row, int* counts, int E) {
  int e = blockIdx.x * 256 + threadIdx.x;
  if (e < E) atomicAdd(&counts[row[e]], 1);
}

// ---------------- parallel scan (3 kernels) ----------------
__global__ __launch_bounds__(1024) void k_scan1(const int* __restrict__ counts, int* __restrict__ rowptr,
                                                int* __restrict__ bsum, int N) {
  __shared__ int sh[1024];
  int t = threadIdx.x, i = blockIdx.x * 1024 + t;
  int c = (i < N) ? counts[i] : 0;
  sh[t] = c;
  __syncthreads();
  for (int d = 1; d < 1024; d <<= 1) {
    int v = (t >= d) ? sh[t - d] : 0;
    __syncthreads();
    sh[t] += v;
    __syncthreads();
  }
  if (i < N) rowptr[i] = sh[t] - c;  // block-local exclusive
  if (t == 1023) bsum[blockIdx.x] = sh[1023];
}

__global__ __launch_bounds__(64) void k_scan2(const int* __restrict__ bsum, int* __restrict__ boff, int G) {
  int t = threadIdx.x;
  int base = 0;
  for (int s = 0; s < G; s += 64) {
    int i = s + t;
    int v = (i < G) ? bsum[i] : 0;
    int orig = v;
    for (int d = 1; d < 64; d <<= 1) {
      int u = __shfl_up(v, d, 64);
      if (t >= d) v += u;
    }
    if (i < G) boff[i] = base + v - orig;
    base += __shfl(v, 63, 64);
  }
}

__global__ __launch_bounds__(1024) void k_scan3(int* __restrict__ rowptr, int* __restrict__ cursor,
                                                const int* __restrict__ boff, int N, int E) {
  int i = blockIdx.x * 1024 + threadIdx.x;
  if (i < N) {
    int v = rowptr[i] + boff[blockIdx.x];
    rowptr[i] = v;
    cursor[i] = v;
  }
  if (i == 0) rowptr[N] = E;
}

__global__ __launch_bounds__(256) void k_fill(const int* __restrict__ row, const int* __restrict__ col,
                                              const float* __restrict__ w, int* cursor,
                                              int2* __restrict__ colw, int E) {
  int e = blockIdx.x * 256 + threadIdx.x;
  if (e < E) {
    int r = row[e];
    int p = atomicAdd(&cursor[r], 1);
    colw[p] = make_int2(col[e], __float_as_int(w[e]));
  }
}

// ---------------- W_in -> bf16 [64 cols][512 k], zero-padded ----------------
__global__ __launch_bounds__(256) void k_wcvt(const float* __restrict__ W, ushort* __restrict__ Wbf) {
  int i = blockIdx.x * 256 + threadIdx.x;
  if (i >= 64 * 512) return;
  int d = i >> 9, k = i & 511;
  Wbf[i] = (k < F_IN) ? f2bf(W[(size_t)k * HD + d]) : (ushort)0;
}

// ---------------- input GEMM via MFMA: h0 = relu(x @ W_in + b), bf16, 1 wave/block ----------------
__global__ __launch_bounds__(64) void k_gemm_in(const float* __restrict__ x,
                                                const ushort* __restrict__ Wbf,
                                                const float* __restrict__ b,
                                                ushort* __restrict__ h0bf, int N) {
  int lane = threadIdx.x;
  int c15 = lane & 15, g4 = lane >> 4;
  int rowA = blockIdx.x * 16 + c15;
  if (rowA >= N) rowA = N - 1;  // clamp; results discarded at store
  const float* xr = x + (size_t)rowA * F_IN;
  int koff = g4 * 8;
  float4v acc[4];
#pragma unroll
  for (int ct = 0; ct < 4; ++ct) acc[ct] = (float4v){0.f, 0.f, 0.f, 0.f};
#pragma unroll 5
  for (int kc = 0; kc < 15; ++kc) {
    int kbase = kc * 32 + koff;
    float4 f0 = *(const float4*)(xr + kbase);
    float4 f1 = *(const float4*)(xr + kbase + 4);
    short8v a;
    a[0] = (short)f2bf(f0.x); a[1] = (short)f2bf(f0.y);
    a[2] = (short)f2bf(f0.z); a[3] = (short)f2bf(f0.w);
    a[4] = (short)f2bf(f1.x); a[5] = (short)f2bf(f1.y);
    a[6] = (short)f2bf(f1.z); a[7] = (short)f2bf(f1.w);
#pragma unroll
    for (int ct = 0; ct < 4; ++ct) {
      const short8v bb = *(const short8v*)&Wbf[((ct * 16 + c15) << 9) + kbase];
      acc[ct] = __builtin_amdgcn_mfma_f32_16x16x32_bf16(a, bb, acc[ct], 0, 0, 0);
    }
  }
  {  // kc = 15 tail: floats 480..499 valid
    int kbase = 480 + koff;
    short8v a;
#pragma unroll
    for (int e = 0; e < 8; ++e) {
      int k = kbase + e;
      a[e] = (short)(k < F_IN ? f2bf(xr[k]) : (ushort)0);
    }
#pragma unroll
    for (int ct = 0; ct < 4; ++ct) {
      const short8v bb = *(const short8v*)&Wbf[((ct * 16 + c15) << 9) + kbase];
      acc[ct] = __builtin_amdgcn_mfma_f32_16x16x32_bf16(a, bb, acc[ct], 0, 0, 0);
    }
  }
  int mbase = blockIdx.x * 16 + g4 * 4;
#pragma unroll
  for (int ct = 0; ct < 4; ++ct) {
    int d = ct * 16 + c15;
    float bias = b[d];
#pragma unroll
    for (int r = 0; r < 4; ++r) {
      int m = mbase + r;
      if (m < N) {
        float v = acc[ct][r] + bias;
        h0bf[(size_t)m * HD + d] = f2bf(fmaxf(v, 0.f));
      }
    }
  }
}

// ---------------- GCN2 layer: LDS-staged edge lists, 2 interleaved rows/wave ----------------
__global__ __launch_bounds__(256) void k_layer(const ushort* __restrict__ hin,
                                               const ushort* __restrict__ h0bf,
                                               const int* __restrict__ rowptr, const int2* __restrict__ colw,
                                               const float* __restrict__ convW, float beta,
                                               ushort* __restrict__ hout, int N) {
  __shared__ float Ml[64][64];          // (1-b)I + b*W
  __shared__ float sup[4][2][64];
  __shared__ int2 ec[4][2][64];
  int tid = threadIdx.x, wv = tid >> 6, t = tid & 63;
  for (int idx = tid; idx < 4096; idx += 256) {
    int i = idx >> 6, j = idx & 63;
    Ml[i][j] = beta * convW[idx] + ((i == j) ? (1.f - beta) : 0.f);
  }
  __syncthreads();
  int nA = blockIdx.x * 8 + wv * 2;
  int nB = nA + 1;
  int e0A = 0, e1A = 0, e0B = 0, e1B = 0;
  if (nA < N) { e0A = rowptr[nA]; e1A = rowptr[nA + 1]; }
  if (nB < N) { e0B = rowptr[nB]; e1B = rowptr[nB + 1]; }
  int degA = e1A - e0A, degB = e1B - e0B;
  int degM = degA > degB ? degA : degB;
  float aA[4] = {0.f, 0.f, 0.f, 0.f}, aB[4] = {0.f, 0.f, 0.f, 0.f};
  for (int base = 0; base < degM; base += 64) {
    int2 ea = (base + t < degA) ? colw[e0A + base + t] : make_int2(0, 0);
    int2 eb = (base + t < degB) ? colw[e0B + base + t] : make_int2(0, 0);
    ec[wv][0][t] = ea;
    ec[wv][1][t] = eb;
    int cA = degA - base; cA = cA < 0 ? 0 : (cA > 64 ? 64 : cA); cA = (cA + 7) & ~7;
    int cB = degB - base; cB = cB < 0 ? 0 : (cB > 64 ? 64 : cB); cB = (cB + 7) & ~7;
    int cM = cA > cB ? cA : cB;
    for (int j = 0; j < cM; j += 8) {
      if (j < cA) {
#pragma unroll
        for (int k = 0; k < 8; ++k) {
          int2 e = ec[wv][0][j + k];
          float g = bf2f(hin[(size_t)e.x * HD + t]);
          aA[k & 3] = fmaf(__int_as_float(e.y), g, aA[k & 3]);
        }
      }
      if (j < cB) {
#pragma unroll
        for (int k = 0; k < 8; ++k) {
          int2 e = ec[wv][1][j + k];
          float g = bf2f(hin[(size_t)e.x * HD + t]);
          aB[k & 3] = fmaf(__int_as_float(e.y), g, aB[k & 3]);
        }
      }
    }
  }
  if (nA < N)
    sup[wv][0][t] = 0.9f * ((aA[0] + aA[1]) + (aA[2] + aA[3])) + 0.1f * bf2f(h0bf[(size_t)nA * HD + t]);
  if (nB < N)
    sup[wv][1][t] = 0.9f * ((aB[0] + aB[1]) + (aB[2] + aB[3])) + 0.1f * bf2f(h0bf[(size_t)nB * HD + t]);
  // matvec: same wave reads its own sup -> no block barrier needed
  if (nA < N) {
    float mv = 0.f;
#pragma unroll
    for (int h = 0; h < 64; ++h) mv = fmaf(sup[wv][0][h], Ml[h][t], mv);
    hout[(size_t)nA * HD + t] = f2bf(fmaxf(mv, 0.f));
  }
  if (nB < N) {
    float mv = 0.f;
#pragma unroll
    for (int h = 0; h < 64; ++h) mv = fmaf(sup[wv][1][h], Ml[h][t], mv);
    hout[(size_t)nB * HD + t] = f2bf(fmaxf(mv, 0.f));
  }
}

// ---------------- group table: g -> (m, l0) ----------------
__global__ __launch_bounds__(512) void k_gtab(int2* __restrict__ gtab) {
  int g = threadIdx.x;
  if (g >= NGRP) return;
  int m = 64, l0 = 65;
  if (g < 297) {
    int cum = 0;
    for (int mm = 0; mm < 65; ++mm) {
      int ng = (65 - mm + 7) >> 3;
      if (g < cum + ng) { m = mm; l0 = mm + (g - cum) * 8; break; }
      cum += ng;
    }
  }
  gtab[g] = make_int2(m, l0);
}

// ---------------- T[r,o] = Wo_o @ V_r^T  (+ linear/const bias terms) ----------------
__global__ __launch_bounds__(256) void k_T(const float* __restrict__ W_out, const float* __restrict__ V_W,
                                           const float* __restrict__ V_b, const float* __restrict__ U_W,
                                           const float* __restrict__ U_b,
                                           float* __restrict__ Tbuf, float* linbuf, float* cbuf) {
  int o = blockIdx.x % NOUT;
  int r = blockIdx.x / NOUT;
  __shared__ float Wo[64][65];
  __shared__ float Vs[64][65];
  __shared__ float t1[64], t2[64];
  int tid = threadIdx.x;
  int tx = tid & 15, ty = tid >> 4;
  for (int idx = tid; idx < 4096; idx += 256) {
    int m = idx >> 6, l = idx & 63;
    Wo[m][l] = W_out[(size_t)idx * NOUT + o];
    Vs[m][l] = V_W[(size_t)(r * 64 + m) * 64 + l];
  }
  __syncthreads();
  float acc[4][4] = {};
  for (int l = 0; l < 64; ++l) {
    float av[4], bv[4];
#pragma unroll
    for (int i = 0; i < 4; ++i) av[i] = Wo[ty * 4 + i][l];
#pragma unroll
    for (int j = 0; j < 4; ++j) bv[j] = Vs[tx * 4 + j][l];
#pragma unroll
    for (int i = 0; i < 4; ++i)
#pragma unroll
      for (int j = 0; j < 4; ++j) acc[i][j] = fmaf(av[i], bv[j], acc[i][j]);
  }
#pragma unroll
  for (int i = 0; i < 4; ++i)
#pragma unroll
    for (int j = 0; j < 4; ++j)
      Tbuf[(((size_t)r * NOUT + o) * 64 + ty * 4 + i) * 64 + tx * 4 + j] = acc[i][j];
  if (tid < 64) {
    float s1 = 0.f, s2 = 0.f;
    for (int l = 0; l < 64; ++l) s1 = fmaf(Wo[tid][l], V_b[r * 64 + l], s1);
    for (int m = 0; m < 64; ++m) s2 = fmaf(Wo[m][tid], U_b[r * 64 + m], s2);
    t1[tid] = s1;
    t2[tid] = s2;
  }
  __syncthreads();
  if (tid < 64) {
    float s = 0.f, s2 = 0.f;
    for (int m = 0; m < 64; ++m) s = fmaf(U_W[(size_t)(r * 64 + tid) * 64 + m], t1[m], s);
    for (int l = 0; l < 64; ++l) s2 = fmaf(Vs[tid][l], t2[l], s2);
    atomicAdd(&linbuf[o * 64 + tid], s + s2);
  }
  if (tid == 0) {
    float s = 0.f;
    for (int m = 0; m < 64; ++m) s = fmaf(U_b[r * 64 + m], t1[m], s);
    atomicAdd(&cbuf[o], s);
  }
}

// ---------------- Q_o = sum_r U_r @ T[r,o]; pack bf16 B-fragments ----------------
__global__ __launch_bounds__(256) void k_Q(const float* __restrict__ U_W, const float* __restrict__ Tbuf,
                                           const float* __restrict__ linbuf, const float* __restrict__ cbuf,
                                           const float* __restrict__ b_out,
                                           const int2* __restrict__ gtab, ushort* __restrict__ Bfrag) {
  int o = blockIdx.x;
  __shared__ float Us[64][65];
  __shared__ float Tb[64][65];
  __shared__ float Q[64][65];
  int tid = threadIdx.x, tx = tid & 15, ty = tid >> 4;
  float acc[4][4] = {};
  for (int r = 0; r < NRANK; ++r) {
    for (int idx = tid; idx < 4096; idx += 256) {
      int a = idx >> 6, mm = idx & 63;
      Us[a][mm] = U_W[(size_t)(r * 64 + a) * 64 + mm];
      Tb[a][mm] = Tbuf[(((size_t)r * NOUT + o) * 64 + a) * 64 + mm];
    }
    __syncthreads();
    for (int mm = 0; mm < 64; ++mm) {
      float av[4], bv[4];
#pragma unroll
      for (int i = 0; i < 4; ++i) av[i] = Us[ty * 4 + i][mm];
#pragma unroll
      for (int j = 0; j < 4; ++j) bv[j] = Tb[mm][tx * 4 + j];
#pragma unroll
      for (int i = 0; i < 4; ++i)
#pragma unroll
        for (int j = 0; j < 4; ++j) acc[i][j] = fmaf(av[i], bv[j], acc[i][j]);
    }
    __syncthreads();
  }
#pragma unroll
  for (int i = 0; i < 4; ++i)
#pragma unroll
    for (int j = 0; j < 4; ++j) Q[ty * 4 + i][tx * 4 + j] = acc[i][j];
  __syncthreads();
  int ot = o >> 4, o15 = o & 15;
  for (int idx = tid; idx < NGRP * 8; idx += 256) {
    int g = idx >> 3, e = idx & 7;
    int2 ml = gtab[g];
    int m = ml.x, l = ml.y + e;
    float v;
    if (l < 64) v = (m == l) ? Q[m][m] : Q[m][l] + Q[l][m];
    else if (l == 64) v = (m == 64) ? (cbuf[o] + b_out[o]) : linbuf[o * 64 + m];
    else v = 0.f;
    int c = g >> 2, g4 = g & 3;
    Bfrag[((((size_t)c * 3 + ot) * 64) + g4 * 16 + o15) * 8 + e] = f2bf(v);
  }
}

// ---------------- logits via MFMA + fused expmap0/proj/log_softmax ----------------
__global__ __launch_bounds__(256) void k_logits(const ushort* __restrict__ hbf,
                                                const ushort* __restrict__ Bfrag,
                                                const int2* __restrict__ gtab,
                                                float* __restrict__ out, int N) {
  __shared__ float eh[128][77];
  __shared__ int2 gs[NGRP];
  int tid = threadIdx.x;
  int n0 = blockIdx.x * 128;
  for (int idx = tid; idx < 128 * 16; idx += 256) {
    int n = idx >> 4, f4 = (idx & 15) << 2;
    int gn = n0 + n;
    float v0 = 0.f, v1 = 0.f, v2 = 0.f, v3 = 0.f;
    if (gn < N) {
      ushort4 u = *(const ushort4*)&hbf[(size_t)gn * HD + f4];
      v0 = bf2f(u.x); v1 = bf2f(u.y); v2 = bf2f(u.z); v3 = bf2f(u.w);
    }
    eh[n][f4] = v0; eh[n][f4 + 1] = v1; eh[n][f4 + 2] = v2; eh[n][f4 + 3] = v3;
  }
  for (int idx = tid; idx < 128 * 13; idx += 256) {
    int n = idx / 13, j = idx - n * 13;
    eh[n][64 + j] = (j == 0) ? 1.f : 0.f;
  }
  for (int idx = tid; idx < NGRP; idx += 256) gs[idx] = gtab[idx];
  __syncthreads();

  int w = tid >> 6, lane = tid & 63;
  int g4 = lane >> 4, c15 = lane & 15;
  float4v acc[2][3];
#pragma unroll
  for (int t = 0; t < 2; ++t)
#pragma unroll
    for (int ot = 0; ot < 3; ++ot) acc[t][ot] = (float4v){0.f, 0.f, 0.f, 0.f};
  const float* ehr0 = &eh[(w * 2 + 0) * 16 + c15][0];
  const float* ehr1 = &eh[(w * 2 + 1) * 16 + c15][0];

  for (int c = 0; c < NCHUNK; ++c) {
    const short8v b0 = *(const short8v*)&Bfrag[(((size_t)c * 3 + 0) * 64 + lane) * 8];
    const short8v b1 = *(const short8v*)&Bfrag[(((size_t)c * 3 + 1) * 64 + lane) * 8];
    const short8v b2 = *(const short8v*)&Bfrag[(((size_t)c * 3 + 2) * 64 + lane) * 8];
    int2 ml = gs[c * 4 + g4];
    int m = ml.x, l0 = ml.y;
    float hm0 = ehr0[m], hm1 = ehr1[m];
    short8v a0, a1;
#pragma unroll
    for (int e = 0; e < 8; ++e) {
      a0[e] = (short)f2bf(hm0 * ehr0[l0 + e]);
      a1[e] = (short)f2bf(hm1 * ehr1[l0 + e]);
    }
    acc[0][0] = __builtin_amdgcn_mfma_f32_16x16x32_bf16(a0, b0, acc[0][0], 0, 0, 0);
    acc[1][0] = __builtin_amdgcn_mfma_f32_16x16x32_bf16(a1, b0, acc[1][0], 0, 0, 0);
    acc[0][1] = __builtin_amdgcn_mfma_f32_16x16x32_bf16(a0, b1, acc[0][1], 0, 0, 0);
    acc[1][1] = __builtin_amdgcn_mfma_f32_16x16x32_bf16(a1, b1, acc[1][1], 0, 0, 0);
    acc[0][2] = __builtin_amdgcn_mfma_f32_16x16x32_bf16(a0, b2, acc[0][2], 0, 0, 0);
    acc[1][2] = __builtin_amdgcn_mfma_f32_16x16x32_bf16(a1, b2, acc[1][2], 0, 0, 0);
  }

  __syncthreads();  // all eh reads done; reuse as logits tile [128][41]
  float* ls = &eh[0][0];
#pragma unroll
  for (int t = 0; t < 2; ++t) {
    int rbase = (w * 2 + t) * 16 + g4 * 4;
#pragma unroll
    for (int ot = 0; ot < 3; ++ot) {
      int o = ot * 16 + c15;
      if (o < NOUT) {
#pragma unroll
        for (int r = 0; r < 4; ++r) ls[(rbase + r) * 41 + o] = acc[t][ot][r];
      }
    }
  }
  __syncthreads();
  if (tid < 128) {
    int n = n0 + tid;
    if (n < N) {
      float v[40];
      float s = 0.f;
#pragma unroll
      for (int i = 0; i < 40; ++i) { v[i] = ls[tid * 41 + i]; s = fmaf(v[i], v[i], s); }
      float un = fmaxf(sqrtf(s), 1e-15f);
      float sc = tanhf(un) / un;
      float s2 = 0.f;
#pragma unroll
      for (int i = 0; i < 40; ++i) { v[i] *= sc; s2 = fmaf(v[i], v[i], s2); }
      float ny = fmaxf(sqrtf(s2), 1e-15f);
      float maxn = 1.0f - 4e-3f;
      if (ny > maxn) {
        float f = maxn / ny;
#pragma unroll
        for (int i = 0; i < 40; ++i) v[i] *= f;
      }
      float vmax = v[0];
#pragma unroll
      for (int i = 1; i < 40; ++i) vmax = fmaxf(vmax, v[i]);
      float se = 0.f;
#pragma unroll
      for (int i = 0; i < 40; ++i) se += expf(v[i] - vmax);
      float lse = logf(se) + vmax;
      float4* q = (float4*)(out + (size_t)n * NOUT);
#pragma unroll
      for (int i = 0; i < 10; ++i) {
        float4 t;
        t.x = v[4 * i] - lse;
        t.y = v[4 * i + 1] - lse;
        t.z = v[4 * i + 2] - lse;
        t.w = v[4 * i + 3] - lse;
        q[i] = t;
      }
    }
  }
}

extern "C" void kernel_launch(void* const* d_in, const int* in_sizes, int n_in,
                              void* d_out, int out_size, void* d_ws, size_t ws_size,
                              hipStream_t stream) {
  const float* x = (const float*)d_in[0];
  const int* erow = (const int*)d_in[1];
  const int* ecol = (const int*)d_in[2];
  const float* ew = (const float*)d_in[3];
  const float* W_in = (const float*)d_in[4];
  const float* b_in = (const float*)d_in[5];
  const float* conv_W = (const float*)d_in[6];
  const float* U_W = (const float*)d_in[7];
  const float* U_b = (const float*)d_in[8];
  const float* V_W = (const float*)d_in[9];
  const float* V_b = (const float*)d_in[10];
  const float* W_out = (const float*)d_in[11];
  const float* b_out = (const float*)d_in[12];
  int N = in_sizes[0] / F_IN;
  int E = in_sizes[1];
  float* out = (float*)d_out;

  char* base = (char*)d_ws;
  size_t off = 0;
  auto alloc = [&](size_t bytes) -> void* {
    void* p = base + off;
    off += (bytes + 255) & ~(size_t)255;
    return p;
  };
  ushort* h0bf = (ushort*)alloc((size_t)N * HD * 2);
  ushort* hbfA = (ushort*)alloc((size_t)N * HD * 2);
  ushort* hbfB = (ushort*)alloc((size_t)N * HD * 2);
  int* rowptr = (int*)alloc((size_t)(N + 1) * 4);
  int* cursor = (int*)alloc((size_t)N * 4);
  int* counts = (int*)alloc((size_t)N * 4);
  int2* colw = (int2*)alloc((size_t)E * 8);
  float* Tbuf = (float*)alloc((size_t)NRANK * NOUT * 64 * 64 * 4);
  ushort* Bfrag = (ushort*)alloc((size_t)NCHUNK * 3 * 64 * 8 * 2);
  ushort* Wbf = (ushort*)alloc((size_t)64 * 512 * 2);
  float* linbuf = (float*)alloc(NOUT * 64 * 4);
  float* cbuf = (float*)alloc(NOUT * 4);
  int2* gtab = (int2*)alloc(NGRP * 8);
  int* bsum = (int*)alloc(64 * 4);
  int* boff = (int*)alloc(64 * 4);

  int G = (N + 1023) / 1024;

  k_zero<<<(N + 255) / 256, 256, 0, stream>>>(counts, linbuf, cbuf, (ushort4*)Bfrag, N);
  k_count<<<(E + 255) / 256, 256, 0, stream>>>(erow, counts, E);
  k_scan1<<<G, 1024, 0, stream>>>(counts, rowptr, bsum, N);
  k_scan2<<<1, 64, 0, stream>>>(bsum, boff, G);
  k_scan3<<<G, 1024, 0, stream>>>(rowptr, cursor, boff, N, E);
  k_fill<<<(E + 255) / 256, 256, 0, stream>>>(erow, ecol, ew, cursor, colw, E);
  k_wcvt<<<128, 256, 0, stream>>>(W_in, Wbf);
  k_gemm_in<<<(N + 15) / 16, 64, 0, stream>>>(x, Wbf, b_in, h0bf, N);
  k_gtab<<<1, 512, 0, stream>>>(gtab);
  k_T<<<NRANK * NOUT, 256, 0, stream>>>(W_out, V_W, V_b, U_W, U_b, Tbuf, linbuf, cbuf);
  k_Q<<<NOUT, 256, 0, stream>>>(U_W, Tbuf, linbuf, cbuf, b_out, gtab, Bfrag);

  const ushort* hin = h0bf;
  ushort* hout = hbfA;
  for (int l = 0; l < NL; ++l) {
    float beta = (float)std::log(0.5 / (double)(l + 1) + 1.0);
    k_layer<<<(N + 7) / 8, 256, 0, stream>>>(hin, h0bf, rowptr, colw,
                                             conv_W + (size_t)l * HD * HD,
                                             beta, hout, N);
    hin = hout;
    hout = (hout == hbfA) ? hbfB : hbfA;
  }
  k_logits<<<(N + 127) / 128, 256, 0, stream>>>(hin, Bfrag, gtab, out, N);
}